// Round 10
// baseline (250.518 us; speedup 1.0000x reference)
//
#include <hip/hip_runtime.h>

// Problem constants: B=32, S=128, H=512, K=8
#define BB 32
#define SS 128
#define HH 512
#define KC 8
#define NN 4096  // KC*HH

typedef __attribute__((ext_vector_type(8))) short bf16x8;
typedef __attribute__((ext_vector_type(4))) float f32x4;

__device__ __forceinline__ unsigned short f2bf(float f) {
  unsigned int u = __float_as_uint(f);
  u += 0x7fffu + ((u >> 16) & 1u);   // round-to-nearest-even
  return (unsigned short)(u >> 16);
}
__device__ __forceinline__ float bf2f(unsigned short h) {
  return __uint_as_float(((unsigned int)h) << 16);
}
__device__ __forceinline__ float tanh_fast(float x) {
  float e = __expf(2.0f * x);
  return 1.0f - 2.0f / (e + 1.0f);
}
__device__ __forceinline__ void async16(const void* g, void* lds) {
  __builtin_amdgcn_global_load_lds(
      (const __attribute__((address_space(1))) unsigned int*)g,
      (__attribute__((address_space(3))) unsigned int*)lds, 16, 0, 0);
}

// ---- conversion kernels (all global stores are ushort4 / 8 B) -------------
// A/P: fp32 [B,S,H] -> hi/lo row-major AND hi-only transposed [B,H,S].
__global__ __launch_bounds__(256) void convert_ap(
    const float* __restrict__ Xa, const float* __restrict__ Xb,
    unsigned short* __restrict__ hia, unsigned short* __restrict__ loa,
    unsigned short* __restrict__ hiTa,
    unsigned short* __restrict__ hib, unsigned short* __restrict__ lob,
    unsigned short* __restrict__ hiTb) {
  const float* X = blockIdx.z ? Xb : Xa;
  unsigned short* hi = blockIdx.z ? hib : hia;
  unsigned short* lo = blockIdx.z ? lob : loa;
  unsigned short* hiT = blockIdx.z ? hiTb : hiTa;
  __shared__ float t[32][33];   // [h_loc][s_loc]
  const int h0 = blockIdx.x * 32;
  const int s0 = (blockIdx.y & 3) * 32;
  const size_t b = blockIdx.y >> 2;
  const int tid = threadIdx.x;
  {
    const int th = tid & 7, ts = tid >> 3;   // h quad, s row
    float4 f = *(const float4*)&X[b * (SS * HH) + (size_t)(s0 + ts) * HH + h0 + th * 4];
    ushort4 h4, l4;
    h4.x = f2bf(f.x); l4.x = f2bf(f.x - bf2f(h4.x));
    h4.y = f2bf(f.y); l4.y = f2bf(f.y - bf2f(h4.y));
    h4.z = f2bf(f.z); l4.z = f2bf(f.z - bf2f(h4.z));
    h4.w = f2bf(f.w); l4.w = f2bf(f.w - bf2f(h4.w));
    size_t o = b * (SS * HH) + (size_t)(s0 + ts) * HH + h0 + th * 4;
    *(ushort4*)&hi[o] = h4;
    *(ushort4*)&lo[o] = l4;
    t[th * 4 + 0][ts] = f.x;
    t[th * 4 + 1][ts] = f.y;
    t[th * 4 + 2][ts] = f.z;
    t[th * 4 + 3][ts] = f.w;
  }
  __syncthreads();
  {
    const int hh = tid >> 3, sq = tid & 7;   // h row, s quad
    ushort4 h4;
    h4.x = f2bf(t[hh][sq * 4 + 0]);
    h4.y = f2bf(t[hh][sq * 4 + 1]);
    h4.z = f2bf(t[hh][sq * 4 + 2]);
    h4.w = f2bf(t[hh][sq * 4 + 3]);
    *(ushort4*)&hiT[b * (SS * HH) + (size_t)(h0 + hh) * SS + s0 + sq * 4] = h4;
  }
}

// G [512, 4096] fp32 -> G^T [4096, 512] (hi, lo) bf16; z selects G1/G2.
__global__ __launch_bounds__(256) void convert_transpose_g(
    const float* __restrict__ Ga, const float* __restrict__ Gb,
    unsigned short* __restrict__ ha, unsigned short* __restrict__ la,
    unsigned short* __restrict__ hb, unsigned short* __restrict__ lb) {
  const float* G = blockIdx.z ? Gb : Ga;
  unsigned short* hiT = blockIdx.z ? hb : ha;
  unsigned short* loT = blockIdx.z ? lb : la;
  __shared__ float t[32][33];   // [n_loc][k_loc]
  const int bx = blockIdx.x * 32;  // n
  const int by = blockIdx.y * 32;  // k
  const int tid = threadIdx.x;
  {
    const int tn = tid & 7, tk = tid >> 3;   // n quad, k row
    float4 f = *(const float4*)&G[(size_t)(by + tk) * NN + bx + tn * 4];
    t[tn * 4 + 0][tk] = f.x;
    t[tn * 4 + 1][tk] = f.y;
    t[tn * 4 + 2][tk] = f.z;
    t[tn * 4 + 3][tk] = f.w;
  }
  __syncthreads();
  {
    const int nn = tid >> 3, kq = tid & 7;   // n row, k quad
    ushort4 h4, l4;
    float f0 = t[nn][kq * 4 + 0], f1 = t[nn][kq * 4 + 1];
    float f2 = t[nn][kq * 4 + 2], f3 = t[nn][kq * 4 + 3];
    h4.x = f2bf(f0); l4.x = f2bf(f0 - bf2f(h4.x));
    h4.y = f2bf(f1); l4.y = f2bf(f1 - bf2f(h4.y));
    h4.z = f2bf(f2); l4.z = f2bf(f2 - bf2f(h4.z));
    h4.w = f2bf(f3); l4.w = f2bf(f3 - bf2f(h4.w));
    size_t o = (size_t)(bx + nn) * HH + by + kq * 4;
    *(ushort4*)&hiT[o] = h4;
    *(ushort4*)&loT[o] = l4;
  }
}

// ---- fused proj+score: block (k, b, br) — unchanged from round 9 ----------
__global__ __launch_bounds__(256, 2) void fused_score(
    const unsigned short* __restrict__ Ahi, const unsigned short* __restrict__ Alo,
    const unsigned short* __restrict__ Phi, const unsigned short* __restrict__ Plo,
    const unsigned short* __restrict__ G1h, const unsigned short* __restrict__ G1l,
    const unsigned short* __restrict__ G2h, const unsigned short* __restrict__ G2l,
    const float* __restrict__ v1, const float* __restrict__ v2,
    float* __restrict__ scoreBuf, int bc) {
  __shared__ char smem[32768];
  unsigned short* sm = (unsigned short*)smem;
  const int k = blockIdx.x;   // fast dim: same-k blocks share an XCD (G L2-resident)
  const int b = blockIdx.y;
  const int brx = blockIdx.z;
  const int tid = threadIdx.x, w = tid >> 6, L = tid & 63;
  const int wm = w >> 1, wn = w & 1;
  const int q = L >> 4, c = L & 15;

  const unsigned short* Ah = Ahi + (size_t)b * SS * HH;
  const unsigned short* Al = Alo + (size_t)b * SS * HH;
  const unsigned short* Gh = brx ? G2h : G1h;
  const unsigned short* Gl = brx ? G2l : G1l;
  const unsigned short* Rh = (brx ? Ahi : Phi) + (size_t)b * SS * HH;
  const unsigned short* Rl = (brx ? Alo : Plo) + (size_t)b * SS * HH;

  const int srow = w * 32 + (L >> 2);
  const int scol = (L & 3) * 8;
  const unsigned short* pAh = Ah + (size_t)srow * HH + scol;
  const unsigned short* pAl = Al + (size_t)srow * HH + scol;
  const unsigned short* pRh = Rh + (size_t)srow * HH + scol;
  const unsigned short* pRl = Rl + (size_t)srow * HH + scol;
  const unsigned lbase = (unsigned)w * 2048;
  const int ar = (wm * 64 + (L & 15)) * 32 + (L >> 4) * 8;
  const int br_ = (wn * 64 + (L & 15)) * 32 + (L >> 4) * 8;

  f32x4 raw[4][4];
#pragma unroll
  for (int i = 0; i < 4; ++i)
#pragma unroll
    for (int j = 0; j < 4; ++j) raw[i][j] = (f32x4)(0.0f);

  for (int gc = 0; gc < 4; ++gc) {
    const size_t n0 = (size_t)k * 512 + (size_t)gc * 128;
    const unsigned short* pBh = Gh + (n0 + srow) * HH + scol;
    const unsigned short* pBl = Gl + (n0 + srow) * HH + scol;
    f32x4 acc[4][4];
#pragma unroll
    for (int i = 0; i < 4; ++i)
#pragma unroll
      for (int j = 0; j < 4; ++j) acc[i][j] = (f32x4)(0.0f);

    for (int kt = 0; kt < 16; ++kt) {
      const int k0 = kt * 32;
      async16(pAh + k0, smem + lbase);
      async16(pAh + k0 + 16 * HH, smem + lbase + 1024);
      async16(pAl + k0, smem + 8192 + lbase);
      async16(pAl + k0 + 16 * HH, smem + 8192 + lbase + 1024);
      async16(pBh + k0, smem + 16384 + lbase);
      async16(pBh + k0 + 16 * HH, smem + 16384 + lbase + 1024);
      async16(pBl + k0, smem + 24576 + lbase);
      async16(pBl + k0 + 16 * HH, smem + 24576 + lbase + 1024);
      __syncthreads();
      bf16x8 ah[4], al[4], bh[4], bl[4];
#pragma unroll
      for (int i = 0; i < 4; ++i) {
        ah[i] = *(const bf16x8*)&sm[ar + i * 512];
        al[i] = *(const bf16x8*)&sm[4096 + ar + i * 512];
        bh[i] = *(const bf16x8*)&sm[8192 + br_ + i * 512];
        bl[i] = *(const bf16x8*)&sm[12288 + br_ + i * 512];
      }
#pragma unroll
      for (int i = 0; i < 4; ++i)
#pragma unroll
        for (int j = 0; j < 4; ++j) {
          acc[i][j] = __builtin_amdgcn_mfma_f32_16x16x32_bf16(ah[i], bh[j], acc[i][j], 0, 0, 0);
          acc[i][j] = __builtin_amdgcn_mfma_f32_16x16x32_bf16(ah[i], bl[j], acc[i][j], 0, 0, 0);
          acc[i][j] = __builtin_amdgcn_mfma_f32_16x16x32_bf16(al[i], bh[j], acc[i][j], 0, 0, 0);
        }
      __syncthreads();
    }

#pragma unroll
    for (int sl = 0; sl < 4; ++sl) {
      const int gg = gc * 128 + sl * 32;
      async16(pRh + gg, smem + 16384 + lbase);
      async16(pRh + gg + 16 * HH, smem + 16384 + lbase + 1024);
      async16(pRl + gg, smem + 24576 + lbase);
      async16(pRl + gg + 16 * HH, smem + 24576 + lbase + 1024);
      if (wn == (sl >> 1)) {
        const int jj0 = (sl & 1) * 2;
#pragma unroll
        for (int i = 0; i < 4; ++i)
#pragma unroll
          for (int jd = 0; jd < 2; ++jd) {
            f32x4 vfr = acc[i][jj0 + jd];
            const int gl = jd * 16 + c;
#pragma unroll
            for (int r = 0; r < 4; ++r) {
              const int row = wm * 64 + i * 16 + q * 4 + r;
              float f = vfr[r];
              unsigned short h = f2bf(f);
              sm[row * 32 + gl] = h;
              sm[4096 + row * 32 + gl] = f2bf(f - bf2f(h));
            }
          }
      }
      __syncthreads();
      bf16x8 sa_h[4], sa_l[4], sb_h[4], sb_l[4];
#pragma unroll
      for (int i = 0; i < 4; ++i) {
        const int ao = (wm * 64 + i * 16 + (L & 15)) * 32 + (L >> 4) * 8;
        sa_h[i] = *(const bf16x8*)&sm[ao];
        sa_l[i] = *(const bf16x8*)&sm[4096 + ao];
      }
#pragma unroll
      for (int j = 0; j < 4; ++j) {
        const int bo = (wn * 64 + j * 16 + (L & 15)) * 32 + (L >> 4) * 8;
        sb_h[j] = *(const bf16x8*)&sm[8192 + bo];
        sb_l[j] = *(const bf16x8*)&sm[12288 + bo];
      }
#pragma unroll
      for (int i = 0; i < 4; ++i)
#pragma unroll
        for (int j = 0; j < 4; ++j) {
          raw[i][j] = __builtin_amdgcn_mfma_f32_16x16x32_bf16(sa_h[i], sb_h[j], raw[i][j], 0, 0, 0);
          raw[i][j] = __builtin_amdgcn_mfma_f32_16x16x32_bf16(sa_h[i], sb_l[j], raw[i][j], 0, 0, 0);
          raw[i][j] = __builtin_amdgcn_mfma_f32_16x16x32_bf16(sa_l[i], sb_h[j], raw[i][j], 0, 0, 0);
        }
      __syncthreads();
    }
  }

  const float vk = (brx ? v2 : v1)[k];
  float* dst = scoreBuf + (((size_t)brx * bc + b) * KC + k) * (SS * SS);
#pragma unroll
  for (int i = 0; i < 4; ++i)
#pragma unroll
    for (int j = 0; j < 4; ++j) {
      const int row0 = wm * 64 + i * 16 + q * 4;
      const int col = wn * 64 + j * 16 + c;
#pragma unroll
      for (int r = 0; r < 4; ++r)
        dst[(size_t)(row0 + r) * SS + col] = vk * tanh_fast(raw[i][j][r]);
    }
}

// ---- k-sum + softmax + PV + residual, fused -------------------------------
// grid (bc*2 groups, 2 s-halves); block covers 64 s-rows x all 512 h.
// LDS: scores fp32 [64][128] @0 (32 KB) | attn bf16 [64][136] @32768 (17 KB)
//      | V staging [128][32] @50176 (8 KB).
__global__ __launch_bounds__(256, 2) void softmax_pv(
    const float* __restrict__ scoreBuf,
    const unsigned short* __restrict__ PTh, const unsigned short* __restrict__ ATh,
    const float* __restrict__ Abase, const float* __restrict__ Pbase,
    float* __restrict__ out1, float* __restrict__ out2, int bc) {
  __shared__ char smem[58368];
  float* sS = (float*)smem;                                  // [64*128]
  unsigned short* attnS = (unsigned short*)(smem + 32768);   // [64][136]
  unsigned short* vsm = (unsigned short*)(smem + 50176);     // [128][32]
  const int x = blockIdx.x;
  const int brx = (x >= bc) ? 1 : 0;
  const int b = x - (brx ? bc : 0);
  const int sh = blockIdx.y;
  const int tid = threadIdx.x;

  // ---- k-sum into LDS (fp32, same accumulation order as round 9) ----
  const float* src = scoreBuf + (size_t)x * KC * (SS * SS) + (size_t)sh * 64 * SS;
#pragma unroll
  for (int it = 0; it < 8; ++it) {
    const int off = (it * 256 + tid) * 4;   // [0, 8192)
    float4 s = make_float4(0.f, 0.f, 0.f, 0.f);
#pragma unroll
    for (int k = 0; k < KC; ++k) {
      float4 a = *(const float4*)&src[(size_t)k * (SS * SS) + off];
      s.x += a.x; s.y += a.y; s.z += a.z; s.w += a.w;
    }
    *(float4*)&sS[off] = s;
  }
  __syncthreads();

  // ---- softmax: 4 threads per s-row (row = tid>>2), 32 t each ----
  {
    const int row = tid >> 2, qtr = tid & 3;
    float* rp = &sS[row * 128 + qtr * 32];
    float mx = rp[0];
#pragma unroll
    for (int j = 1; j < 32; ++j) mx = fmaxf(mx, rp[j]);
    mx = fmaxf(mx, __shfl_xor(mx, 1, 4));
    mx = fmaxf(mx, __shfl_xor(mx, 2, 4));
    float ssum = 0.0f;
#pragma unroll
    for (int j = 0; j < 32; ++j) {
      float p = __expf(rp[j] - mx);
      rp[j] = p;
      ssum += p;
    }
    ssum += __shfl_xor(ssum, 1, 4);
    ssum += __shfl_xor(ssum, 2, 4);
    float inv = 1.0f / ssum;
    unsigned short* ap = &attnS[row * 136 + qtr * 32];
#pragma unroll
    for (int j = 0; j < 16; ++j) {
      ushort2 h2;
      h2.x = f2bf(rp[j * 2] * inv);
      h2.y = f2bf(rp[j * 2 + 1] * inv);
      *(ushort2*)&ap[j * 2] = h2;
    }
  }
  __syncthreads();

  // ---- PV hi-only: out[64 s x 512 h] = base + attn @ V ----
  const unsigned short* Vbase = (brx ? ATh : PTh) + (size_t)b * HH * SS;
  const float* base = (brx ? Pbase : Abase) + (size_t)b * SS * HH;
  float* outp = (brx ? out2 : out1) + (size_t)b * SS * HH;
  const int w = tid >> 6, L = tid & 63;
  const int wm = w >> 1, wn = w & 1;
  const int q = L >> 4, c = L & 15;
  const int brow = w * 32 + (L >> 2);
  const int scol = (L & 3) * 8;

  for (int hc = 0; hc < 4; ++hc) {
    f32x4 acc[2][4];
#pragma unroll
    for (int i = 0; i < 2; ++i)
#pragma unroll
      for (int j = 0; j < 4; ++j) acc[i][j] = (f32x4)(0.0f);
    const unsigned short* Vh = Vbase + (size_t)(hc * 128) * SS;
#pragma unroll
    for (int kt = 0; kt < 4; ++kt) {
      const int k0 = kt * 32;
      async16(Vh + (size_t)brow * SS + k0 + scol, (char*)vsm + w * 2048);
      async16(Vh + (size_t)(brow + 16) * SS + k0 + scol, (char*)vsm + w * 2048 + 1024);
      __syncthreads();
      bf16x8 af[2], bf[4];
#pragma unroll
      for (int i = 0; i < 2; ++i)
        af[i] = *(const bf16x8*)&attnS[(wm * 32 + i * 16 + (L & 15)) * 136 + k0 + (L >> 4) * 8];
#pragma unroll
      for (int j = 0; j < 4; ++j)
        bf[j] = *(const bf16x8*)&vsm[(wn * 64 + j * 16 + (L & 15)) * 32 + (L >> 4) * 8];
#pragma unroll
      for (int i = 0; i < 2; ++i)
#pragma unroll
        for (int j = 0; j < 4; ++j)
          acc[i][j] = __builtin_amdgcn_mfma_f32_16x16x32_bf16(af[i], bf[j], acc[i][j], 0, 0, 0);
      __syncthreads();
    }
#pragma unroll
    for (int i = 0; i < 2; ++i)
#pragma unroll
      for (int j = 0; j < 4; ++j) {
        const int srow = sh * 64 + wm * 32 + i * 16 + q * 4;
        const int hcol = hc * 128 + wn * 64 + j * 16 + c;
#pragma unroll
        for (int r = 0; r < 4; ++r) {
          size_t o = (size_t)(srow + r) * HH + hcol;
          outp[o] = base[o] + acc[i][j][r];
        }
      }
  }
}

extern "C" void kernel_launch(void* const* d_in, const int* in_sizes, int n_in,
                              void* d_out, int out_size, void* d_ws, size_t ws_size,
                              hipStream_t stream) {
  const float* A  = (const float*)d_in[0];
  const float* P  = (const float*)d_in[1];
  const float* G1 = (const float*)d_in[2];
  const float* G2 = (const float*)d_in[3];
  const float* v1 = (const float*)d_in[4];
  const float* v2 = (const float*)d_in[5];
  float* out1 = (float*)d_out;
  float* out2 = out1 + (size_t)BB * SS * HH;

  const size_t NA = (size_t)BB * SS * HH;  // 2M
  const size_t NG = (size_t)HH * KC * HH;  // 2M
  unsigned short* Ahi = (unsigned short*)d_ws;
  unsigned short* Alo = Ahi + NA;
  unsigned short* Phi = Alo + NA;
  unsigned short* Plo = Phi + NA;
  unsigned short* G1h = Plo + NA;
  unsigned short* G1l = G1h + NG;
  unsigned short* G2h = G1l + NG;
  unsigned short* G2l = G2h + NG;
  unsigned short* ATh = G2l + NG;
  unsigned short* PTh = ATh + NA;

  const size_t fixedBytes = (6 * NA + 4 * NG) * sizeof(unsigned short);  // 40 MB
  const size_t perB = 2 * (size_t)KC * SS * SS * sizeof(float);  // 1 MB/batch
  size_t rem = ws_size > fixedBytes ? ws_size - fixedBytes : 0;
  int Bc = (int)(rem / perB);
  if (Bc < 1) Bc = 1;
  if (Bc > BB) Bc = BB;
  float* scoreBuf = (float*)((char*)d_ws + fixedBytes);

  convert_ap<<<dim3(HH / 32, (SS / 32) * BB, 2), 256, 0, stream>>>(
      A, P, Ahi, Alo, ATh, Phi, Plo, PTh);
  convert_transpose_g<<<dim3(NN / 32, HH / 32, 2), 256, 0, stream>>>(
      G1, G2, G1h, G1l, G2h, G2l);

  for (int b0 = 0; b0 < BB; b0 += Bc) {
    int bc = (Bc < BB - b0) ? Bc : (BB - b0);
    size_t off = (size_t)b0 * SS * HH;  // element offset (both layouts)
    fused_score<<<dim3(KC, bc, 2), 256, 0, stream>>>(
        Ahi + off, Alo + off, Phi + off, Plo + off,
        G1h, G1l, G2h, G2l, v1, v2, scoreBuf, bc);
    softmax_pv<<<dim3(bc * 2, 2), 256, 0, stream>>>(
        scoreBuf, PTh + off, ATh + off, A + off, P + off,
        out1 + off, out2 + off, bc);
  }
}